// Round 7
// baseline (295.042 us; speedup 1.0000x reference)
//
#include <hip/hip_runtime.h>
#include <hip/hip_bf16.h>
#include <cstddef>
#include <cstdint>

// Hyena1D: y = irfft(rfft(x, axis=1) * H) * amp_gain, H real per (bin, channel).
//
// Channel-pair packing: z_g(t) = x[t][2g] + i*x[t][2g+1];
//   Y[k] = hp*Z[k] + hm*conj(Z[4096-k]), hp=(HA+HB)/2, hm=(HA-HB)/2.
//
// r7 structure: WAVE-LOCAL FFT. 64-thread blocks; lane j holds z[j+64a],
// a=0..63 in registers (128 VGPR). 4096 = 64x64:
//   fft64(regs) -> twiddle W4096^{-j*r} (chained cmul, 1 sincos) ->
//   64x64 LDS transpose (wave-coherent, NO barriers) -> fft64(regs)
//   => X[r+64s] at lane r, reg s.
//   Filter: partner of k=r+64s is (lane (64-r)&63, reg 63-s) -> ds_bpermute
//   with STATIC reg indices; lane 0 self-paired via masked branch; lane 32
//   self-consistent through the bpermute path.
//   Inverse mirrors forward. Zero __syncthreads in the whole kernel.
// r5/r6 post-mortem: phase/barrier-serialized structure was the limiter
// (9 barriers, 5 LDS RTs; occupancy up didn't help). This has 0 barriers,
// 2 LDS RTs, 5 sincos/thread (was 61).

#define B_ 4
#define T_ 4096
#define D_ 1024
#define D2_ 512
#define NBINS 2049

// W64 twiddles: WC[j]=cos(pi j/32), WS[j]=sin(pi j/32)
constexpr float WC[32] = {
    1.0f, 0.9951847266721969f, 0.9807852804032304f, 0.9569403357322088f,
    0.9238795325112867f, 0.8819212643483551f, 0.8314696123025452f, 0.7730104533627370f,
    0.7071067811865476f, 0.6343932841636455f, 0.5555702330196022f, 0.4713967368259976f,
    0.3826834323650898f, 0.2902846772544623f, 0.1950903220161283f, 0.0980171403295606f,
    0.0f, -0.0980171403295606f, -0.1950903220161283f, -0.2902846772544623f,
    -0.3826834323650898f, -0.4713967368259976f, -0.5555702330196022f, -0.6343932841636455f,
    -0.7071067811865476f, -0.7730104533627370f, -0.8314696123025452f, -0.8819212643483551f,
    -0.9238795325112867f, -0.9569403357322088f, -0.9807852804032304f, -0.9951847266721969f};
constexpr float WS[32] = {
    0.0f, 0.0980171403295606f, 0.1950903220161283f, 0.2902846772544623f,
    0.3826834323650898f, 0.4713967368259976f, 0.5555702330196022f, 0.6343932841636455f,
    0.7071067811865476f, 0.7730104533627370f, 0.8314696123025452f, 0.8819212643483551f,
    0.9238795325112867f, 0.9569403357322088f, 0.9807852804032304f, 0.9951847266721969f,
    1.0f, 0.9951847266721969f, 0.9807852804032304f, 0.9569403357322088f,
    0.9238795325112867f, 0.8819212643483551f, 0.8314696123025452f, 0.7730104533627370f,
    0.7071067811865476f, 0.6343932841636455f, 0.5555702330196022f, 0.4713967368259976f,
    0.3826834323650898f, 0.2902846772544623f, 0.1950903220161283f, 0.0980171403295606f};

template <int SGN>
__device__ __forceinline__ void fft64(float (&vr)[64], float (&vi)[64]) {
#pragma unroll
  for (int i = 0; i < 64; ++i) {
    const int j = ((i & 1) << 5) | ((i & 2) << 3) | ((i & 4) << 1) |
                  ((i & 8) >> 1) | ((i & 16) >> 3) | ((i & 32) >> 5);
    if (j > i) {
      float t = vr[i]; vr[i] = vr[j]; vr[j] = t;
      t = vi[i]; vi[i] = vi[j]; vi[j] = t;
    }
  }
#pragma unroll
  for (int s = 1; s <= 6; ++s) {
    const int L = 1 << s, hh = L >> 1, step = 64 >> s;
#pragma unroll
    for (int k0 = 0; k0 < 64; k0 += L)
#pragma unroll
      for (int j = 0; j < hh; ++j) {
        const float wr = WC[j * step];
        const float wi = (float)SGN * WS[j * step];
        const int ia = k0 + j, ib = ia + hh;
        const float tr = wr * vr[ib] - wi * vi[ib];
        const float ti = wr * vi[ib] + wi * vr[ib];
        vr[ib] = vr[ia] - tr; vi[ib] = vi[ia] - ti;
        vr[ia] += tr; vi[ia] += ti;
      }
  }
}

__device__ __forceinline__ float bperm_f(int addr, float v) {
  return __int_as_float(__builtin_amdgcn_ds_bpermute(addr, __float_as_int(v)));
}

// ---- filter MLP ----
__global__ void k_filter_h(const float* __restrict__ W1, const float* __restrict__ b1,
                           float* __restrict__ h) {
  const int bin = blockIdx.x * 256 + threadIdx.x;
  if (bin >= NBINS) return;
  constexpr float invf[8] = {1.0f, 0.31622776601683794f, 0.1f, 0.031622776601683794f,
                             0.01f, 3.1622776601683794e-3f, 1.0e-3f, 3.1622776601683794e-4f};
  float pe[16];
#pragma unroll
  for (int i = 0; i < 8; ++i) {
    const float a = (float)bin * invf[i];
    pe[2 * i] = sinf(a);
    pe[2 * i + 1] = cosf(a);
  }
#pragma unroll
  for (int m = 0; m < 32; ++m) {
    float s = b1[m];
#pragma unroll
    for (int i = 0; i < 16; ++i) s += pe[i] * W1[i * 32 + m];
    h[bin * 32 + m] = s / (1.0f + expf(-s));  // silu
  }
}

// HT[g][bin] = (hp, hm); 1/4096 folded into unpack
__global__ void k_filter_HT(const float* __restrict__ h, const float* __restrict__ W2,
                            const float* __restrict__ b2, float2* __restrict__ HT) {
  const int bin = blockIdx.x * 256 + threadIdx.x;
  const int g = blockIdx.y;
  if (bin >= NBINS) return;
  float sA = b2[2 * g], sB = b2[2 * g + 1];
#pragma unroll
  for (int m = 0; m < 32; ++m) {
    const float hv = h[bin * 32 + m];
    sA += hv * W2[m * D_ + 2 * g];
    sB += hv * W2[m * D_ + 2 * g + 1];
  }
  HT[(size_t)g * NBINS + bin] = make_float2((sA + sB) * 0.5f, (sA - sB) * 0.5f);
}

// ---- T1: x[b,t,d] -> Z[b,g,t] (packed pairs) ----
__global__ __launch_bounds__(256, 8) void k_pack_t(const float2* __restrict__ x2,
                                                   float2* __restrict__ Z) {
  __shared__ float2 tile[64][33];
  const int tid = threadIdx.x;
  const int g0 = blockIdx.x * 32;
  const int t0 = blockIdx.y * 64;
  const int b = blockIdx.z;
#pragma unroll
  for (int it = 0; it < 8; ++it) {
    const int l = tid + 256 * it;
    const int r = l >> 5, c = l & 31;
    tile[r][c] = x2[((size_t)b * T_ + t0 + r) * D2_ + g0 + c];
  }
  __syncthreads();
#pragma unroll
  for (int it = 0; it < 8; ++it) {
    const int l = tid + 256 * it;
    const int gg = l >> 6, tt = l & 63;
    Z[((size_t)b * D2_ + g0 + gg) * T_ + t0 + tt] = tile[tt][gg];
  }
}

// ---- F: wave-local full FFT/filter/iFFT per (g,b), in-place on Z row ----
__global__ __launch_bounds__(64, 2) void k_fft_fused(float2* __restrict__ Z,
                                                     const float2* __restrict__ HT) {
  __shared__ float Tr[4096];  // 16 KB
  __shared__ float Ti[4096];  // 16 KB
  const int lane = threadIdx.x;  // 0..63
  const int g = blockIdx.x;
  const int b = blockIdx.y;
  float2* __restrict__ Zrow = Z + ((size_t)b * D2_ + g) * T_;
  const float2* __restrict__ HTg = HT + (size_t)g * NBINS;
  constexpr float C1f = -6.28318530717958647692f / 4096.0f;
  constexpr float C1i = 6.28318530717958647692f / 4096.0f;

  float vr[64], vi[64];
#pragma unroll
  for (int a = 0; a < 64; ++a) {
    const float2 t = Zrow[lane + 64 * a];
    vr[a] = t.x; vi[a] = t.y;
  }
  fft64<-1>(vr, vi);  // reg r = F_lane[r]

  // twiddle W4096^{-lane*r} via chained cmul (1 sincos)
  {
    float wc, ws_;
    __sincosf(C1f * (float)lane, &ws_, &wc);
    float cr = wc, ci = ws_;
    {
      const float t = vr[1] * cr - vi[1] * ci;
      vi[1] = vr[1] * ci + vi[1] * cr; vr[1] = t;
    }
#pragma unroll
    for (int r = 2; r < 64; ++r) {
      const float nc = cr * wc - ci * ws_;
      const float ns = cr * ws_ + ci * wc;
      cr = nc; ci = ns;
      const float t = vr[r] * cr - vi[r] * ci;
      vi[r] = vr[r] * ci + vi[r] * cr; vr[r] = t;
    }
  }

  // transpose 1: lane j reg r -> lane r reg j (wave-coherent, no barrier)
  {
#pragma unroll
    for (int r = 0; r < 64; ++r) {
      const int e = (r >> 5) * 2048 + lane * 32 + ((r & 31) ^ (lane & 31));
      Tr[e] = vr[r]; Ti[e] = vi[r];
    }
    const int hb = (lane >> 5) * 2048, col = lane & 31;
#pragma unroll
    for (int j = 0; j < 64; ++j) {
      const int e = hb + j * 32 + (col ^ (j & 31));
      vr[j] = Tr[e]; vi[j] = Ti[e];
    }
  }
  fft64<-1>(vr, vi);  // reg s = X[lane + 64 s]

  // ---- filter ----
  const int paddr = (((64 - lane) & 63) << 2);
  if (lane != 0) {
#pragma unroll
    for (int s = 0; s < 32; ++s) {
      const float xsr = bperm_f(paddr, vr[63 - s]);
      const float xsi = bperm_f(paddr, vi[63 - s]);
      const float xbr = bperm_f(paddr, vr[s]);
      const float xbi = bperm_f(paddr, vi[s]);
      const float2 hs = HTg[lane + 64 * s];        // km of k = lane+64s (<=2047)
      const float2 hb2 = HTg[64 - lane + 64 * s];  // km of k = lane+64(63-s)
      const float ar = vr[s], ai = vi[s], br = vr[63 - s], bi = vi[63 - s];
      vr[s] = hs.x * ar + hs.y * xsr;
      vi[s] = hs.x * ai - hs.y * xsi;
      vr[63 - s] = hb2.x * br + hb2.y * xbr;
      vi[63 - s] = hb2.x * bi - hb2.y * xbi;
    }
  } else {
    {  // k = 0
      const float2 hv = HTg[0];
      const float r0 = vr[0], i0 = vi[0];
      vr[0] = (hv.x + hv.y) * r0; vi[0] = (hv.x - hv.y) * i0;
    }
    {  // k = 2048
      const float2 hv = HTg[2048];
      const float r0 = vr[32], i0 = vi[32];
      vr[32] = (hv.x + hv.y) * r0; vi[32] = (hv.x - hv.y) * i0;
    }
#pragma unroll
    for (int s = 1; s < 32; ++s) {  // pairs (64s, 4096-64s) share bin 64s
      const float2 hv = HTg[64 * s];
      const float ar = vr[s], ai = vi[s], br = vr[64 - s], bi = vi[64 - s];
      vr[s] = hv.x * ar + hv.y * br;
      vi[s] = hv.x * ai - hv.y * bi;
      vr[64 - s] = hv.x * br + hv.y * ar;
      vi[64 - s] = hv.x * bi - hv.y * ai;
    }
  }

  // ---- inverse ----
  fft64<1>(vr, vi);  // over s -> reg j = A_lane[j]
  {  // twiddle W4096^{+lane*j}
    float wc, ws_;
    __sincosf(C1i * (float)lane, &ws_, &wc);
    float cr = wc, ci = ws_;
    {
      const float t = vr[1] * cr - vi[1] * ci;
      vi[1] = vr[1] * ci + vi[1] * cr; vr[1] = t;
    }
#pragma unroll
    for (int r = 2; r < 64; ++r) {
      const float nc = cr * wc - ci * ws_;
      const float ns = cr * ws_ + ci * wc;
      cr = nc; ci = ns;
      const float t = vr[r] * cr - vi[r] * ci;
      vi[r] = vr[r] * ci + vi[r] * cr; vr[r] = t;
    }
  }
  // transpose 2 (same buffers; same-wave DS is in-order -> WAR safe)
  {
#pragma unroll
    for (int r = 0; r < 64; ++r) {
      const int e = (r >> 5) * 2048 + lane * 32 + ((r & 31) ^ (lane & 31));
      Tr[e] = vr[r]; Ti[e] = vi[r];
    }
    const int hb = (lane >> 5) * 2048, col = lane & 31;
#pragma unroll
    for (int j = 0; j < 64; ++j) {
      const int e = hb + j * 32 + (col ^ (j & 31));
      vr[j] = Tr[e]; vi[j] = Ti[e];
    }
  }
  fft64<1>(vr, vi);  // reg a = z_out[lane + 64 a] (unnormalized)

#pragma unroll
  for (int a = 0; a < 64; ++a)
    Zrow[lane + 64 * a] = make_float2(vr[a], vi[a]);
}

// ---- T2: Z[b,g,t] -> y[b,t,d], * amp/4096 ----
__global__ __launch_bounds__(256, 8) void k_unpack_t(const float2* __restrict__ Z,
                                                     const float2* __restrict__ amp2,
                                                     float2* __restrict__ y2) {
  __shared__ float2 tile[64][33];
  const int tid = threadIdx.x;
  const int g0 = blockIdx.x * 32;
  const int t0 = blockIdx.y * 64;
  const int b = blockIdx.z;
#pragma unroll
  for (int it = 0; it < 8; ++it) {
    const int l = tid + 256 * it;
    const int gg = l >> 6, tt = l & 63;
    tile[tt][gg] = Z[((size_t)b * D2_ + g0 + gg) * T_ + t0 + tt];
  }
  __syncthreads();
#pragma unroll
  for (int it = 0; it < 8; ++it) {
    const int l = tid + 256 * it;
    const int r = l >> 5, c = l & 31;
    const float2 t = tile[r][c];
    const float2 av = amp2[g0 + c];
    constexpr float invN = 1.0f / 4096.0f;
    y2[((size_t)b * T_ + t0 + r) * D2_ + g0 + c] =
        make_float2(t.x * av.x * invN, t.y * av.y * invN);
  }
}

extern "C" void kernel_launch(void* const* d_in, const int* in_sizes, int n_in,
                              void* d_out, int out_size, void* d_ws, size_t ws_size,
                              hipStream_t stream) {
  const float* x = (const float*)d_in[0];
  const float* W1 = (const float*)d_in[1];
  const float* b1 = (const float*)d_in[2];
  const float* W2 = (const float*)d_in[3];
  const float* b2 = (const float*)d_in[4];
  const float* amp = (const float*)d_in[5];
  float* out = (float*)d_out;

  float2* Z = (float2*)d_ws;  // 64 MB
  float2* HT = (float2*)((char*)d_ws + (size_t)B_ * D2_ * T_ * sizeof(float2));  // 8.4 MB
  float* h = (float*)((char*)HT + (size_t)D2_ * NBINS * sizeof(float2));  // 262 KB

  k_filter_h<<<dim3((NBINS + 255) / 256), 256, 0, stream>>>(W1, b1, h);
  k_filter_HT<<<dim3((NBINS + 255) / 256, D2_), 256, 0, stream>>>(h, W2, b2, HT);
  k_pack_t<<<dim3(D2_ / 32, T_ / 64, B_), 256, 0, stream>>>((const float2*)x, Z);
  k_fft_fused<<<dim3(D2_, B_), 64, 0, stream>>>(Z, HT);
  k_unpack_t<<<dim3(D2_ / 32, T_ / 64, B_), 256, 0, stream>>>(Z, (const float2*)amp,
                                                              (float2*)out);
}

// Round 8
// 174.095 us; speedup vs baseline: 1.6947x; 1.6947x over previous
//
#include <hip/hip_runtime.h>
#include <hip/hip_bf16.h>
#include <cstddef>
#include <cstdint>

// Hyena1D: y = irfft(rfft(x, axis=1) * H) * amp_gain, H real per (bin, channel).
//
// Channel-pair packing: z_g(t) = x[t][2g] + i*x[t][2g+1];
//   Y[k] = hp*Z[k] + hm*conj(Z[4096-k]), hp=(HA+HB)/2, hm=(HA-HB)/2.
//
// WAVE-LOCAL FFT (r7 structure, functionally verified on HW):
// 64-thread blocks; lane j holds z[j+64a] in regs. 4096 = 64x64:
// fft64 -> chained twiddle -> LDS transpose (wave-coherent, 0 barriers)
// -> fft64 -> filter (partner via ds_bpermute, static reg indices)
// -> mirror inverse. Zero __syncthreads.
//
// r7 post-mortem: __launch_bounds__(64,2) capped VGPRs at 128 -> full spill
// (VGPR_Count=128, WRITE 201MB vs 64 ideal, VALUBusy 10%). Same trap as r1.
// FIX: (64,1) -> allocator free to ~240 (r2 precedent: 244, no spill).
// Also: single 16KB transpose buffer (re pass then im pass; same-wave DS is
// in-order, validated r7) -> LDS no longer binds occupancy (8 blocks/CU).

#define B_ 4
#define T_ 4096
#define D_ 1024
#define D2_ 512
#define NBINS 2049

// W64 twiddles: WC[j]=cos(pi j/32), WS[j]=sin(pi j/32)
constexpr float WC[32] = {
    1.0f, 0.9951847266721969f, 0.9807852804032304f, 0.9569403357322088f,
    0.9238795325112867f, 0.8819212643483551f, 0.8314696123025452f, 0.7730104533627370f,
    0.7071067811865476f, 0.6343932841636455f, 0.5555702330196022f, 0.4713967368259976f,
    0.3826834323650898f, 0.2902846772544623f, 0.1950903220161283f, 0.0980171403295606f,
    0.0f, -0.0980171403295606f, -0.1950903220161283f, -0.2902846772544623f,
    -0.3826834323650898f, -0.4713967368259976f, -0.5555702330196022f, -0.6343932841636455f,
    -0.7071067811865476f, -0.7730104533627370f, -0.8314696123025452f, -0.8819212643483551f,
    -0.9238795325112867f, -0.9569403357322088f, -0.9807852804032304f, -0.9951847266721969f};
constexpr float WS[32] = {
    0.0f, 0.0980171403295606f, 0.1950903220161283f, 0.2902846772544623f,
    0.3826834323650898f, 0.4713967368259976f, 0.5555702330196022f, 0.6343932841636455f,
    0.7071067811865476f, 0.7730104533627370f, 0.8314696123025452f, 0.8819212643483551f,
    0.9238795325112867f, 0.9569403357322088f, 0.9807852804032304f, 0.9951847266721969f,
    1.0f, 0.9951847266721969f, 0.9807852804032304f, 0.9569403357322088f,
    0.9238795325112867f, 0.8819212643483551f, 0.8314696123025452f, 0.7730104533627370f,
    0.7071067811865476f, 0.6343932841636455f, 0.5555702330196022f, 0.4713967368259976f,
    0.3826834323650898f, 0.2902846772544623f, 0.1950903220161283f, 0.0980171403295606f};

template <int SGN>
__device__ __forceinline__ void fft64(float (&vr)[64], float (&vi)[64]) {
#pragma unroll
  for (int i = 0; i < 64; ++i) {
    const int j = ((i & 1) << 5) | ((i & 2) << 3) | ((i & 4) << 1) |
                  ((i & 8) >> 1) | ((i & 16) >> 3) | ((i & 32) >> 5);
    if (j > i) {
      float t = vr[i]; vr[i] = vr[j]; vr[j] = t;
      t = vi[i]; vi[i] = vi[j]; vi[j] = t;
    }
  }
#pragma unroll
  for (int s = 1; s <= 6; ++s) {
    const int L = 1 << s, hh = L >> 1, step = 64 >> s;
#pragma unroll
    for (int k0 = 0; k0 < 64; k0 += L)
#pragma unroll
      for (int j = 0; j < hh; ++j) {
        const float wr = WC[j * step];
        const float wi = (float)SGN * WS[j * step];
        const int ia = k0 + j, ib = ia + hh;
        const float tr = wr * vr[ib] - wi * vi[ib];
        const float ti = wr * vi[ib] + wi * vr[ib];
        vr[ib] = vr[ia] - tr; vi[ib] = vi[ia] - ti;
        vr[ia] += tr; vi[ia] += ti;
      }
  }
}

__device__ __forceinline__ float bperm_f(int addr, float v) {
  return __int_as_float(__builtin_amdgcn_ds_bpermute(addr, __float_as_int(v)));
}

// ---- filter MLP ----
__global__ void k_filter_h(const float* __restrict__ W1, const float* __restrict__ b1,
                           float* __restrict__ h) {
  const int bin = blockIdx.x * 256 + threadIdx.x;
  if (bin >= NBINS) return;
  constexpr float invf[8] = {1.0f, 0.31622776601683794f, 0.1f, 0.031622776601683794f,
                             0.01f, 3.1622776601683794e-3f, 1.0e-3f, 3.1622776601683794e-4f};
  float pe[16];
#pragma unroll
  for (int i = 0; i < 8; ++i) {
    const float a = (float)bin * invf[i];
    pe[2 * i] = sinf(a);
    pe[2 * i + 1] = cosf(a);
  }
#pragma unroll
  for (int m = 0; m < 32; ++m) {
    float s = b1[m];
#pragma unroll
    for (int i = 0; i < 16; ++i) s += pe[i] * W1[i * 32 + m];
    h[bin * 32 + m] = s / (1.0f + expf(-s));  // silu
  }
}

// HT[g][bin] = (hp, hm); 1/4096 folded into unpack
__global__ void k_filter_HT(const float* __restrict__ h, const float* __restrict__ W2,
                            const float* __restrict__ b2, float2* __restrict__ HT) {
  const int bin = blockIdx.x * 256 + threadIdx.x;
  const int g = blockIdx.y;
  if (bin >= NBINS) return;
  float sA = b2[2 * g], sB = b2[2 * g + 1];
#pragma unroll
  for (int m = 0; m < 32; ++m) {
    const float hv = h[bin * 32 + m];
    sA += hv * W2[m * D_ + 2 * g];
    sB += hv * W2[m * D_ + 2 * g + 1];
  }
  HT[(size_t)g * NBINS + bin] = make_float2((sA + sB) * 0.5f, (sA - sB) * 0.5f);
}

// ---- T1: x[b,t,d] -> Z[b,g,t] (packed pairs) ----
__global__ __launch_bounds__(256, 8) void k_pack_t(const float2* __restrict__ x2,
                                                   float2* __restrict__ Z) {
  __shared__ float2 tile[64][33];
  const int tid = threadIdx.x;
  const int g0 = blockIdx.x * 32;
  const int t0 = blockIdx.y * 64;
  const int b = blockIdx.z;
#pragma unroll
  for (int it = 0; it < 8; ++it) {
    const int l = tid + 256 * it;
    const int r = l >> 5, c = l & 31;
    tile[r][c] = x2[((size_t)b * T_ + t0 + r) * D2_ + g0 + c];
  }
  __syncthreads();
#pragma unroll
  for (int it = 0; it < 8; ++it) {
    const int l = tid + 256 * it;
    const int gg = l >> 6, tt = l & 63;
    Z[((size_t)b * D2_ + g0 + gg) * T_ + t0 + tt] = tile[tt][gg];
  }
}

// ---- F: wave-local full FFT/filter/iFFT per (g,b), in-place on Z row ----
__global__ __launch_bounds__(64, 1) void k_fft_fused(float2* __restrict__ Z,
                                                     const float2* __restrict__ HT) {
  __shared__ float Tbuf[4096];  // 16 KB, reused re-pass then im-pass
  const int lane = threadIdx.x;  // 0..63
  const int g = blockIdx.x;
  const int b = blockIdx.y;
  float2* __restrict__ Zrow = Z + ((size_t)b * D2_ + g) * T_;
  const float2* __restrict__ HTg = HT + (size_t)g * NBINS;
  constexpr float C1f = -6.28318530717958647692f / 4096.0f;
  constexpr float C1i = 6.28318530717958647692f / 4096.0f;

  float vr[64], vi[64];
#pragma unroll
  for (int a = 0; a < 64; ++a) {
    const float2 t = Zrow[lane + 64 * a];
    vr[a] = t.x; vi[a] = t.y;
  }
  fft64<-1>(vr, vi);  // reg r = F_lane[r]

  // twiddle W4096^{-lane*r} via chained cmul (1 sincos)
  {
    float wc, ws_;
    __sincosf(C1f * (float)lane, &ws_, &wc);
    float cr = wc, ci = ws_;
    {
      const float t = vr[1] * cr - vi[1] * ci;
      vi[1] = vr[1] * ci + vi[1] * cr; vr[1] = t;
    }
#pragma unroll
    for (int r = 2; r < 64; ++r) {
      const float nc = cr * wc - ci * ws_;
      const float ns = cr * ws_ + ci * wc;
      cr = nc; ci = ns;
      const float t = vr[r] * cr - vi[r] * ci;
      vi[r] = vr[r] * ci + vi[r] * cr; vr[r] = t;
    }
  }

  // transpose 1: lane j reg r -> lane r reg j (wave-coherent, no barrier)
  // re pass then im pass through ONE 16KB buffer (same-wave DS in-order)
  {
    const int hb = (lane >> 5) * 2048, col = lane & 31;
#pragma unroll
    for (int r = 0; r < 64; ++r)
      Tbuf[(r >> 5) * 2048 + lane * 32 + ((r & 31) ^ (lane & 31))] = vr[r];
#pragma unroll
    for (int j = 0; j < 64; ++j) vr[j] = Tbuf[hb + j * 32 + (col ^ (j & 31))];
#pragma unroll
    for (int r = 0; r < 64; ++r)
      Tbuf[(r >> 5) * 2048 + lane * 32 + ((r & 31) ^ (lane & 31))] = vi[r];
#pragma unroll
    for (int j = 0; j < 64; ++j) vi[j] = Tbuf[hb + j * 32 + (col ^ (j & 31))];
  }
  fft64<-1>(vr, vi);  // reg s = X[lane + 64 s]

  // ---- filter ----
  const int paddr = (((64 - lane) & 63) << 2);
  if (lane != 0) {
#pragma unroll
    for (int s = 0; s < 32; ++s) {
      const float xsr = bperm_f(paddr, vr[63 - s]);
      const float xsi = bperm_f(paddr, vi[63 - s]);
      const float xbr = bperm_f(paddr, vr[s]);
      const float xbi = bperm_f(paddr, vi[s]);
      const float2 hs = HTg[lane + 64 * s];        // km of k = lane+64s (<=2047)
      const float2 hb2 = HTg[64 - lane + 64 * s];  // km of k = lane+64(63-s)
      const float ar = vr[s], ai = vi[s], br = vr[63 - s], bi = vi[63 - s];
      vr[s] = hs.x * ar + hs.y * xsr;
      vi[s] = hs.x * ai - hs.y * xsi;
      vr[63 - s] = hb2.x * br + hb2.y * xbr;
      vi[63 - s] = hb2.x * bi - hb2.y * xbi;
    }
  } else {
    {  // k = 0
      const float2 hv = HTg[0];
      const float r0 = vr[0], i0 = vi[0];
      vr[0] = (hv.x + hv.y) * r0; vi[0] = (hv.x - hv.y) * i0;
    }
    {  // k = 2048
      const float2 hv = HTg[2048];
      const float r0 = vr[32], i0 = vi[32];
      vr[32] = (hv.x + hv.y) * r0; vi[32] = (hv.x - hv.y) * i0;
    }
#pragma unroll
    for (int s = 1; s < 32; ++s) {  // pairs (64s, 4096-64s) share bin 64s
      const float2 hv = HTg[64 * s];
      const float ar = vr[s], ai = vi[s], br = vr[64 - s], bi = vi[64 - s];
      vr[s] = hv.x * ar + hv.y * br;
      vi[s] = hv.x * ai - hv.y * bi;
      vr[64 - s] = hv.x * br + hv.y * ar;
      vi[64 - s] = hv.x * bi - hv.y * ai;
    }
  }

  // ---- inverse ----
  fft64<1>(vr, vi);  // over s -> reg j = A_lane[j]
  {  // twiddle W4096^{+lane*j}
    float wc, ws_;
    __sincosf(C1i * (float)lane, &ws_, &wc);
    float cr = wc, ci = ws_;
    {
      const float t = vr[1] * cr - vi[1] * ci;
      vi[1] = vr[1] * ci + vi[1] * cr; vr[1] = t;
    }
#pragma unroll
    for (int r = 2; r < 64; ++r) {
      const float nc = cr * wc - ci * ws_;
      const float ns = cr * ws_ + ci * wc;
      cr = nc; ci = ns;
      const float t = vr[r] * cr - vi[r] * ci;
      vi[r] = vr[r] * ci + vi[r] * cr; vr[r] = t;
    }
  }
  // transpose 2 (same buffer; same-wave DS in-order -> safe)
  {
    const int hb = (lane >> 5) * 2048, col = lane & 31;
#pragma unroll
    for (int r = 0; r < 64; ++r)
      Tbuf[(r >> 5) * 2048 + lane * 32 + ((r & 31) ^ (lane & 31))] = vr[r];
#pragma unroll
    for (int j = 0; j < 64; ++j) vr[j] = Tbuf[hb + j * 32 + (col ^ (j & 31))];
#pragma unroll
    for (int r = 0; r < 64; ++r)
      Tbuf[(r >> 5) * 2048 + lane * 32 + ((r & 31) ^ (lane & 31))] = vi[r];
#pragma unroll
    for (int j = 0; j < 64; ++j) vi[j] = Tbuf[hb + j * 32 + (col ^ (j & 31))];
  }
  fft64<1>(vr, vi);  // reg a = z_out[lane + 64 a] (unnormalized)

#pragma unroll
  for (int a = 0; a < 64; ++a)
    Zrow[lane + 64 * a] = make_float2(vr[a], vi[a]);
}

// ---- T2: Z[b,g,t] -> y[b,t,d], * amp/4096 ----
__global__ __launch_bounds__(256, 8) void k_unpack_t(const float2* __restrict__ Z,
                                                     const float2* __restrict__ amp2,
                                                     float2* __restrict__ y2) {
  __shared__ float2 tile[64][33];
  const int tid = threadIdx.x;
  const int g0 = blockIdx.x * 32;
  const int t0 = blockIdx.y * 64;
  const int b = blockIdx.z;
#pragma unroll
  for (int it = 0; it < 8; ++it) {
    const int l = tid + 256 * it;
    const int gg = l >> 6, tt = l & 63;
    tile[tt][gg] = Z[((size_t)b * D2_ + g0 + gg) * T_ + t0 + tt];
  }
  __syncthreads();
#pragma unroll
  for (int it = 0; it < 8; ++it) {
    const int l = tid + 256 * it;
    const int r = l >> 5, c = l & 31;
    const float2 t = tile[r][c];
    const float2 av = amp2[g0 + c];
    constexpr float invN = 1.0f / 4096.0f;
    y2[((size_t)b * T_ + t0 + r) * D2_ + g0 + c] =
        make_float2(t.x * av.x * invN, t.y * av.y * invN);
  }
}

extern "C" void kernel_launch(void* const* d_in, const int* in_sizes, int n_in,
                              void* d_out, int out_size, void* d_ws, size_t ws_size,
                              hipStream_t stream) {
  const float* x = (const float*)d_in[0];
  const float* W1 = (const float*)d_in[1];
  const float* b1 = (const float*)d_in[2];
  const float* W2 = (const float*)d_in[3];
  const float* b2 = (const float*)d_in[4];
  const float* amp = (const float*)d_in[5];
  float* out = (float*)d_out;

  float2* Z = (float2*)d_ws;  // 64 MB
  float2* HT = (float2*)((char*)d_ws + (size_t)B_ * D2_ * T_ * sizeof(float2));  // 8.4 MB
  float* h = (float*)((char*)HT + (size_t)D2_ * NBINS * sizeof(float2));  // 262 KB

  k_filter_h<<<dim3((NBINS + 255) / 256), 256, 0, stream>>>(W1, b1, h);
  k_filter_HT<<<dim3((NBINS + 255) / 256, D2_), 256, 0, stream>>>(h, W2, b2, HT);
  k_pack_t<<<dim3(D2_ / 32, T_ / 64, B_), 256, 0, stream>>>((const float2*)x, Z);
  k_fft_fused<<<dim3(D2_, B_), 64, 0, stream>>>(Z, HT);
  k_unpack_t<<<dim3(D2_ / 32, T_ / 64, B_), 256, 0, stream>>>(Z, (const float2*)amp,
                                                              (float2*)out);
}

// Round 9
// 155.099 us; speedup vs baseline: 1.9023x; 1.1225x over previous
//
#include <hip/hip_runtime.h>
#include <hip/hip_bf16.h>
#include <cstddef>
#include <cstdint>

// Hyena1D: y = irfft(rfft(x, axis=1) * H) * amp_gain, H real per (bin, channel).
//
// Channel-pair packing: z_g(t) = x[t][2g] + i*x[t][2g+1];
//   Y[k] = hp*Z[k] + hm*conj(Z[4096-k]), hp=(HA+HB)/2, hm=(HA-HB)/2.
// Pipeline: T1 transpose -> F fused radix-16^3 FFT/filter/iFFT per (b,g) row
// (r5 structure: 256 thr, 16 pts/thr, fp32 float2 LDS, 9 barriers, verified
// 78us) -> T2 transpose + amp/4096.
//
// r8 post-mortem: wave-local variant is latency-starved by construction
// (224 VGPR -> 2 waves/SIMD, nothing hides the dependent chain; 169us).
// r9 = r5 + two measured fixes:
//  (a) chained-cmul twiddles: 4 sincos/thread (was 61) - twiddles depend only
//      on thread index, not data.
//  (b) H table generated in scrambled lane-coalesced order HTS[g][256*s2+tid]
//      (was bit-swapped gather -> 64 cache lines per load instruction).

#define B_ 4
#define T_ 4096
#define D_ 1024
#define D2_ 512
#define NBINS 2049

constexpr float WC16[8] = {1.f, 0.9238795325112867f, 0.7071067811865476f,
                           0.3826834323650898f, 0.f, -0.3826834323650898f,
                           -0.7071067811865476f, -0.9238795325112867f};
constexpr float WS16[8] = {0.f, 0.3826834323650898f, 0.7071067811865476f,
                           0.9238795325112867f, 1.f, 0.9238795325112867f,
                           0.7071067811865476f, 0.3826834323650898f};

template <int SGN>
__device__ __forceinline__ void dft16(float (&vr)[16], float (&vi)[16]) {
#pragma unroll
  for (int i = 0; i < 16; ++i) {
    const int j = ((i & 1) << 3) | ((i & 2) << 1) | ((i & 4) >> 1) | ((i & 8) >> 3);
    if (j > i) {
      float t = vr[i]; vr[i] = vr[j]; vr[j] = t;
      t = vi[i]; vi[i] = vi[j]; vi[j] = t;
    }
  }
#pragma unroll
  for (int s = 1; s <= 4; ++s) {
    const int L = 1 << s, hh = L >> 1, step = 16 >> s;
#pragma unroll
    for (int k0 = 0; k0 < 16; k0 += L)
#pragma unroll
      for (int j = 0; j < hh; ++j) {
        const float wr = WC16[j * step];
        const float wi = (float)SGN * WS16[j * step];
        const int ia = k0 + j, ib = ia + hh;
        const float tr = wr * vr[ib] - wi * vi[ib];
        const float ti = wr * vi[ib] + wi * vr[ib];
        vr[ib] = vr[ia] - tr; vi[ib] = vi[ia] - ti;
        vr[ia] += tr; vi[ia] += ti;
      }
  }
}

// apply acc *= w chain over regs [r0..15], multiplying (vr[r],vi[r]) by acc
__device__ __forceinline__ void chain_twiddle(float (&vr)[16], float (&vi)[16],
                                              int r0, float wc, float ws) {
  float ar = wc, ai = ws;
#pragma unroll
  for (int r = 1; r < 16; ++r) {
    if (r >= r0) {
      const float tr = vr[r] * ar - vi[r] * ai;
      vi[r] = vr[r] * ai + vi[r] * ar;
      vr[r] = tr;
    }
    if (r < 15) {
      const float nr = ar * wc - ai * ws;
      const float ni = ar * ws + ai * wc;
      ar = nr; ai = ni;
    }
  }
}

// ---- filter MLP ----
__global__ void k_filter_h(const float* __restrict__ W1, const float* __restrict__ b1,
                           float* __restrict__ h) {
  const int bin = blockIdx.x * 256 + threadIdx.x;
  if (bin >= NBINS) return;
  constexpr float invf[8] = {1.0f, 0.31622776601683794f, 0.1f, 0.031622776601683794f,
                             0.01f, 3.1622776601683794e-3f, 1.0e-3f, 3.1622776601683794e-4f};
  float pe[16];
#pragma unroll
  for (int i = 0; i < 8; ++i) {
    const float a = (float)bin * invf[i];
    pe[2 * i] = sinf(a);
    pe[2 * i + 1] = cosf(a);
  }
#pragma unroll
  for (int m = 0; m < 32; ++m) {
    float s = b1[m];
#pragma unroll
    for (int i = 0; i < 16; ++i) s += pe[i] * W1[i * 32 + m];
    h[bin * 32 + m] = s / (1.0f + expf(-s));  // silu
  }
}

// HTS[g][q]: (hp,hm) at km(k(q)), q = 256*s2 + tid, k = (tid>>4)+16*(tid&15)+256*s2.
// Matches the fused filter's per-lane access -> coalesced 512B loads there.
__global__ void k_filter_HTS(const float* __restrict__ h, const float* __restrict__ W2,
                             const float* __restrict__ b2, float2* __restrict__ HTS) {
  const int q = blockIdx.x * 256 + threadIdx.x;
  const int g = blockIdx.y;
  const int tid = q & 255, s2 = q >> 8;
  const int k = (tid >> 4) + 16 * (tid & 15) + 256 * s2;
  const int km = (k <= 2048) ? k : 4096 - k;
  float sA = b2[2 * g], sB = b2[2 * g + 1];
#pragma unroll
  for (int m = 0; m < 32; ++m) {
    const float hv = h[km * 32 + m];
    sA += hv * W2[m * D_ + 2 * g];
    sB += hv * W2[m * D_ + 2 * g + 1];
  }
  HTS[(size_t)g * 4096 + q] = make_float2((sA + sB) * 0.5f, (sA - sB) * 0.5f);
}

// ---- T1: x[b,t,d] -> Z[b,g,t] (packed pairs) ----
__global__ __launch_bounds__(256, 8) void k_pack_t(const float2* __restrict__ x2,
                                                   float2* __restrict__ Z) {
  __shared__ float2 tile[64][33];
  const int tid = threadIdx.x;
  const int g0 = blockIdx.x * 32;
  const int t0 = blockIdx.y * 64;
  const int b = blockIdx.z;
#pragma unroll
  for (int it = 0; it < 8; ++it) {
    const int l = tid + 256 * it;
    const int r = l >> 5, c = l & 31;
    tile[r][c] = x2[((size_t)b * T_ + t0 + r) * D2_ + g0 + c];
  }
  __syncthreads();
#pragma unroll
  for (int it = 0; it < 8; ++it) {
    const int l = tid + 256 * it;
    const int gg = l >> 6, tt = l & 63;
    Z[((size_t)b * D2_ + g0 + gg) * T_ + t0 + tt] = tile[tt][gg];
  }
}

// ---- F: full FFT/filter/iFFT per (b,g), in-place on Z row ----
__global__ __launch_bounds__(256, 4) void k_fft_fused(float2* __restrict__ Z,
                                                      const float2* __restrict__ HTS) {
  __shared__ float2 S[4096];  // 32 KB fp32
  const int tid = threadIdx.x;
  const int b = blockIdx.x;
  const int g = blockIdx.y;
  float2* __restrict__ Zrow = Z + ((size_t)b * D2_ + g) * T_;
  const float2* __restrict__ HTSg = HTS + (size_t)g * 4096;
  constexpr float C1f = -6.28318530717958647692f / 4096.0f;
  constexpr float C2f = -6.28318530717958647692f / 256.0f;
  constexpr float C1i = 6.28318530717958647692f / 4096.0f;

  float vr[16], vi[16];
  // fwd stage 1: thread j: u[a]=z[j+256a]; DFT16 a->r; *W4096^{-rj}; S[256r+j]
  {
    const int j = tid;
#pragma unroll
    for (int a = 0; a < 16; ++a) {
      const float2 t = Zrow[j + 256 * a];
      vr[a] = t.x; vi[a] = t.y;
    }
    dft16<-1>(vr, vi);
    float wc, ws;
    __sincosf(C1f * (float)j, &ws, &wc);
    chain_twiddle(vr, vi, 1, wc, ws);
#pragma unroll
    for (int r = 0; r < 16; ++r) S[256 * r + j] = make_float2(vr[r], vi[r]);
  }
  __syncthreads();
  const int rr = tid >> 4, ii = tid & 15;
  float w2c, w2s;
  __sincosf(C2f * (float)ii, &w2s, &w2c);
  // fwd stage 2
  {
#pragma unroll
    for (int a = 0; a < 16; ++a) {
      const float2 t = S[256 * rr + ii + 16 * a];
      vr[a] = t.x; vi[a] = t.y;
    }
    __syncthreads();  // WAR
    dft16<-1>(vr, vi);
    chain_twiddle(vr, vi, 1, w2c, w2s);
#pragma unroll
    for (int r2 = 0; r2 < 16; ++r2)
      S[256 * ii + 16 * rr + (r2 ^ ii)] = make_float2(vr[r2], vi[r2]);
  }
  __syncthreads();
  // fwd stage 3: vr[s2] = X[k], k = rr + 16*ii + 256*s2
  {
#pragma unroll
    for (int i2 = 0; i2 < 16; ++i2) {
      const float2 t = S[256 * i2 + 16 * rr + (ii ^ i2)];
      vr[i2] = t.x; vi[i2] = t.y;
    }
    __syncthreads();  // WAR
    dft16<-1>(vr, vi);
  }
  // filter: prefetch hv coalesced; X swizzle-stored; partner conj from LDS
  float2 hv[16];
  {
#pragma unroll
    for (int s2 = 0; s2 < 16; ++s2) hv[s2] = HTSg[256 * s2 + tid];
#pragma unroll
    for (int s2 = 0; s2 < 16; ++s2)
      S[256 * s2 + 16 * ii + (rr ^ ii)] = make_float2(vr[s2], vi[s2]);
    __syncthreads();
#pragma unroll
    for (int s2 = 0; s2 < 16; ++s2) {
      const int k = rr + 16 * ii + 256 * s2;
      const int kp = (4096 - k) & 4095;
      const int d0 = kp & 15, d1 = (kp >> 4) & 15, d2 = kp >> 8;
      const float2 xp = S[256 * d2 + 16 * d1 + (d0 ^ d1)];
      const float yr = hv[s2].x * vr[s2] + hv[s2].y * xp.x;
      const float yi = hv[s2].x * vi[s2] - hv[s2].y * xp.y;
      vr[s2] = yr; vi[s2] = yi;
    }
  }
  __syncthreads();  // WAR before inv writes
  // inv stage A: DFT16; *W256^{+ii*j0} (conj of w2); S[256j0+16rr+(ii^j0)]
  {
    dft16<1>(vr, vi);
    chain_twiddle(vr, vi, 1, w2c, -w2s);
#pragma unroll
    for (int j0 = 0; j0 < 16; ++j0)
      S[256 * j0 + 16 * rr + (ii ^ j0)] = make_float2(vr[j0], vi[j0]);
  }
  __syncthreads();
  // inv stage B: read S[256*ii+16*rr+(r2^ii)]; DFT16;
  // *W4096^{+rr*(ii+16*j1)} = base exp(i C1i rr ii), step exp(i C1i 16 rr)
  {
#pragma unroll
    for (int r2 = 0; r2 < 16; ++r2) {
      const float2 t = S[256 * ii + 16 * rr + (r2 ^ ii)];
      vr[r2] = t.x; vi[r2] = t.y;
    }
    __syncthreads();  // WAR
    dft16<1>(vr, vi);
    float bc, bs, sc, ss;
    __sincosf(C1i * (float)(rr * ii), &bs, &bc);
    __sincosf(C1i * (float)(16 * rr), &ss, &sc);
    float ar = bc, ai = bs;
#pragma unroll
    for (int j1 = 0; j1 < 16; ++j1) {
      const float tr = vr[j1] * ar - vi[j1] * ai;
      vi[j1] = vr[j1] * ai + vi[j1] * ar;
      vr[j1] = tr;
      if (j1 < 15) {
        const float nr = ar * sc - ai * ss;
        const float ni = ar * ss + ai * sc;
        ar = nr; ai = ni;
      }
    }
#pragma unroll
    for (int j1 = 0; j1 < 16; ++j1)
      S[256 * rr + ii + 16 * j1] = make_float2(vr[j1], vi[j1]);
  }
  __syncthreads();
  // inv stage C: thread j: u[r]=S[256r+j]; DFT16; z[j+256a] (1/N in T2)
  {
    const int j = tid;
#pragma unroll
    for (int r = 0; r < 16; ++r) {
      const float2 t = S[256 * r + j];
      vr[r] = t.x; vi[r] = t.y;
    }
    dft16<1>(vr, vi);
#pragma unroll
    for (int a = 0; a < 16; ++a) Zrow[j + 256 * a] = make_float2(vr[a], vi[a]);
  }
}

// ---- T2: Z[b,g,t] -> y[b,t,d], * amp/4096 ----
__global__ __launch_bounds__(256, 8) void k_unpack_t(const float2* __restrict__ Z,
                                                     const float2* __restrict__ amp2,
                                                     float2* __restrict__ y2) {
  __shared__ float2 tile[64][33];
  const int tid = threadIdx.x;
  const int g0 = blockIdx.x * 32;
  const int t0 = blockIdx.y * 64;
  const int b = blockIdx.z;
#pragma unroll
  for (int it = 0; it < 8; ++it) {
    const int l = tid + 256 * it;
    const int gg = l >> 6, tt = l & 63;
    tile[tt][gg] = Z[((size_t)b * D2_ + g0 + gg) * T_ + t0 + tt];
  }
  __syncthreads();
#pragma unroll
  for (int it = 0; it < 8; ++it) {
    const int l = tid + 256 * it;
    const int r = l >> 5, c = l & 31;
    const float2 t = tile[r][c];
    const float2 av = amp2[g0 + c];
    constexpr float invN = 1.0f / 4096.0f;
    y2[((size_t)b * T_ + t0 + r) * D2_ + g0 + c] =
        make_float2(t.x * av.x * invN, t.y * av.y * invN);
  }
}

extern "C" void kernel_launch(void* const* d_in, const int* in_sizes, int n_in,
                              void* d_out, int out_size, void* d_ws, size_t ws_size,
                              hipStream_t stream) {
  const float* x = (const float*)d_in[0];
  const float* W1 = (const float*)d_in[1];
  const float* b1 = (const float*)d_in[2];
  const float* W2 = (const float*)d_in[3];
  const float* b2 = (const float*)d_in[4];
  const float* amp = (const float*)d_in[5];
  float* out = (float*)d_out;

  float2* Z = (float2*)d_ws;  // 64 MB
  float2* HTS = (float2*)((char*)d_ws + (size_t)B_ * D2_ * T_ * sizeof(float2));  // 16 MB
  float* h = (float*)((char*)HTS + (size_t)D2_ * 4096 * sizeof(float2));  // 262 KB

  k_filter_h<<<dim3((NBINS + 255) / 256), 256, 0, stream>>>(W1, b1, h);
  k_filter_HTS<<<dim3(16, D2_), 256, 0, stream>>>(h, W2, b2, HTS);
  k_pack_t<<<dim3(D2_ / 32, T_ / 64, B_), 256, 0, stream>>>((const float2*)x, Z);
  k_fft_fused<<<dim3(B_, D2_), 256, 0, stream>>>(Z, HTS);
  k_unpack_t<<<dim3(D2_ / 32, T_ / 64, B_), 256, 0, stream>>>(Z, (const float2*)amp,
                                                              (float2*)out);
}

// Round 10
// 153.368 us; speedup vs baseline: 1.9238x; 1.0113x over previous
//
#include <hip/hip_runtime.h>
#include <hip/hip_bf16.h>
#include <cstddef>
#include <cstdint>

// Hyena1D: y = irfft(rfft(x, axis=1) * H) * amp_gain, H real per (bin, channel).
//
// Channel-pair packing: z_g(t) = x[t][2g] + i*x[t][2g+1];
//   Y[k] = hp*Z[k] + hm*conj(Z[4096-k]), hp=(HA+HB)/2, hm=(HA-HB)/2.
// Pipeline: T1 transpose -> F fused radix-16^3 FFT/filter/iFFT per (b,g) row
// -> T2 transpose + amp/4096.
//
// r9 post-mortem: (1) grid (B_,D2_) put same-g blocks on different XCDs ->
// HTS L2 reuse lost (FETCH 55->118MB). (2) chained-cmul twiddles serialized
// the dependency chain (VALUBusy 34->27.7) - latency-bound kernel wants ILP,
// not fewer ops. r10: r5 structure (fp32 LDS, independent per-element sincos,
// grid (D2_,B_): same-g -> same XCD since 512%8==0) + r9's coalesced HTS
// table + 5 blocks/CU (LDS 5x32KB = 160KB exactly, launch_bounds(256,5)).

#define B_ 4
#define T_ 4096
#define D_ 1024
#define D2_ 512
#define NBINS 2049

constexpr float WC16[8] = {1.f, 0.9238795325112867f, 0.7071067811865476f,
                           0.3826834323650898f, 0.f, -0.3826834323650898f,
                           -0.7071067811865476f, -0.9238795325112867f};
constexpr float WS16[8] = {0.f, 0.3826834323650898f, 0.7071067811865476f,
                           0.9238795325112867f, 1.f, 0.9238795325112867f,
                           0.7071067811865476f, 0.3826834323650898f};

template <int SGN>
__device__ __forceinline__ void dft16(float (&vr)[16], float (&vi)[16]) {
#pragma unroll
  for (int i = 0; i < 16; ++i) {
    const int j = ((i & 1) << 3) | ((i & 2) << 1) | ((i & 4) >> 1) | ((i & 8) >> 3);
    if (j > i) {
      float t = vr[i]; vr[i] = vr[j]; vr[j] = t;
      t = vi[i]; vi[i] = vi[j]; vi[j] = t;
    }
  }
#pragma unroll
  for (int s = 1; s <= 4; ++s) {
    const int L = 1 << s, hh = L >> 1, step = 16 >> s;
#pragma unroll
    for (int k0 = 0; k0 < 16; k0 += L)
#pragma unroll
      for (int j = 0; j < hh; ++j) {
        const float wr = WC16[j * step];
        const float wi = (float)SGN * WS16[j * step];
        const int ia = k0 + j, ib = ia + hh;
        const float tr = wr * vr[ib] - wi * vi[ib];
        const float ti = wr * vi[ib] + wi * vr[ib];
        vr[ib] = vr[ia] - tr; vi[ib] = vi[ia] - ti;
        vr[ia] += tr; vi[ia] += ti;
      }
  }
}

__device__ __forceinline__ void twiddle(float& xr, float& xi, float ang) {
  float sn, cs;
  __sincosf(ang, &sn, &cs);
  const float r = xr * cs - xi * sn;
  xi = xr * sn + xi * cs;
  xr = r;
}

// ---- filter MLP ----
__global__ void k_filter_h(const float* __restrict__ W1, const float* __restrict__ b1,
                           float* __restrict__ h) {
  const int bin = blockIdx.x * 256 + threadIdx.x;
  if (bin >= NBINS) return;
  constexpr float invf[8] = {1.0f, 0.31622776601683794f, 0.1f, 0.031622776601683794f,
                             0.01f, 3.1622776601683794e-3f, 1.0e-3f, 3.1622776601683794e-4f};
  float pe[16];
#pragma unroll
  for (int i = 0; i < 8; ++i) {
    const float a = (float)bin * invf[i];
    pe[2 * i] = sinf(a);
    pe[2 * i + 1] = cosf(a);
  }
#pragma unroll
  for (int m = 0; m < 32; ++m) {
    float s = b1[m];
#pragma unroll
    for (int i = 0; i < 16; ++i) s += pe[i] * W1[i * 32 + m];
    h[bin * 32 + m] = s / (1.0f + expf(-s));  // silu
  }
}

// HTS[g][q]: (hp,hm) at km(k(q)), q = 256*s2 + tid, k = (tid>>4)+16*(tid&15)+256*s2.
// Matches the fused filter's per-lane access -> coalesced 512B loads there.
__global__ void k_filter_HTS(const float* __restrict__ h, const float* __restrict__ W2,
                             const float* __restrict__ b2, float2* __restrict__ HTS) {
  const int q = blockIdx.x * 256 + threadIdx.x;
  const int g = blockIdx.y;
  const int tid = q & 255, s2 = q >> 8;
  const int k = (tid >> 4) + 16 * (tid & 15) + 256 * s2;
  const int km = (k <= 2048) ? k : 4096 - k;
  float sA = b2[2 * g], sB = b2[2 * g + 1];
#pragma unroll
  for (int m = 0; m < 32; ++m) {
    const float hv = h[km * 32 + m];
    sA += hv * W2[m * D_ + 2 * g];
    sB += hv * W2[m * D_ + 2 * g + 1];
  }
  HTS[(size_t)g * 4096 + q] = make_float2((sA + sB) * 0.5f, (sA - sB) * 0.5f);
}

// ---- T1: x[b,t,d] -> Z[b,g,t] (packed pairs) ----
__global__ __launch_bounds__(256, 8) void k_pack_t(const float2* __restrict__ x2,
                                                   float2* __restrict__ Z) {
  __shared__ float2 tile[64][33];
  const int tid = threadIdx.x;
  const int g0 = blockIdx.x * 32;
  const int t0 = blockIdx.y * 64;
  const int b = blockIdx.z;
#pragma unroll
  for (int it = 0; it < 8; ++it) {
    const int l = tid + 256 * it;
    const int r = l >> 5, c = l & 31;
    tile[r][c] = x2[((size_t)b * T_ + t0 + r) * D2_ + g0 + c];
  }
  __syncthreads();
#pragma unroll
  for (int it = 0; it < 8; ++it) {
    const int l = tid + 256 * it;
    const int gg = l >> 6, tt = l & 63;
    Z[((size_t)b * D2_ + g0 + gg) * T_ + t0 + tt] = tile[tt][gg];
  }
}

// ---- F: full FFT/filter/iFFT per (g,b), in-place on Z row ----
__global__ __launch_bounds__(256, 5) void k_fft_fused(float2* __restrict__ Z,
                                                      const float2* __restrict__ HTS) {
  __shared__ float2 S[4096];  // 32 KB fp32; 5 blocks/CU = 160 KB exactly
  const int tid = threadIdx.x;
  const int g = blockIdx.x;
  const int b = blockIdx.y;
  float2* __restrict__ Zrow = Z + ((size_t)b * D2_ + g) * T_;
  const float2* __restrict__ HTSg = HTS + (size_t)g * 4096;
  constexpr float C1f = -6.28318530717958647692f / 4096.0f;
  constexpr float C2f = -6.28318530717958647692f / 256.0f;
  constexpr float C1i = 6.28318530717958647692f / 4096.0f;
  constexpr float C2i = 6.28318530717958647692f / 256.0f;

  float vr[16], vi[16];
  // fwd stage 1: thread j: u[a]=z[j+256a]; DFT16 a->r; *W4096^{-rj}; S[256r+j]
  {
    const int j = tid;
#pragma unroll
    for (int a = 0; a < 16; ++a) {
      const float2 t = Zrow[j + 256 * a];
      vr[a] = t.x; vi[a] = t.y;
    }
    dft16<-1>(vr, vi);
#pragma unroll
    for (int r = 1; r < 16; ++r) twiddle(vr[r], vi[r], C1f * (float)(r * j));
#pragma unroll
    for (int r = 0; r < 16; ++r) S[256 * r + j] = make_float2(vr[r], vi[r]);
  }
  __syncthreads();
  const int rr = tid >> 4, ii = tid & 15;
  // fwd stage 2
  {
#pragma unroll
    for (int a = 0; a < 16; ++a) {
      const float2 t = S[256 * rr + ii + 16 * a];
      vr[a] = t.x; vi[a] = t.y;
    }
    __syncthreads();  // WAR
    dft16<-1>(vr, vi);
#pragma unroll
    for (int r2 = 1; r2 < 16; ++r2) twiddle(vr[r2], vi[r2], C2f * (float)(r2 * ii));
#pragma unroll
    for (int r2 = 0; r2 < 16; ++r2)
      S[256 * ii + 16 * rr + (r2 ^ ii)] = make_float2(vr[r2], vi[r2]);
  }
  __syncthreads();
  // fwd stage 3: vr[s2] = X[k], k = rr + 16*ii + 256*s2
  {
#pragma unroll
    for (int i2 = 0; i2 < 16; ++i2) {
      const float2 t = S[256 * i2 + 16 * rr + (ii ^ i2)];
      vr[i2] = t.x; vi[i2] = t.y;
    }
    __syncthreads();  // WAR
    dft16<-1>(vr, vi);
  }
  // filter: prefetch hv coalesced; X swizzle-stored; partner conj from LDS
  float2 hv[16];
  {
#pragma unroll
    for (int s2 = 0; s2 < 16; ++s2) hv[s2] = HTSg[256 * s2 + tid];
#pragma unroll
    for (int s2 = 0; s2 < 16; ++s2)
      S[256 * s2 + 16 * ii + (rr ^ ii)] = make_float2(vr[s2], vi[s2]);
    __syncthreads();
#pragma unroll
    for (int s2 = 0; s2 < 16; ++s2) {
      const int k = rr + 16 * ii + 256 * s2;
      const int kp = (4096 - k) & 4095;
      const int d0 = kp & 15, d1 = (kp >> 4) & 15, d2 = kp >> 8;
      const float2 xp = S[256 * d2 + 16 * d1 + (d0 ^ d1)];
      const float yr = hv[s2].x * vr[s2] + hv[s2].y * xp.x;
      const float yi = hv[s2].x * vi[s2] - hv[s2].y * xp.y;
      vr[s2] = yr; vi[s2] = yi;
    }
  }
  __syncthreads();  // WAR before inv writes
  // inv stage A: DFT16; *W256^{+ii*j0}; S[256j0+16rr+(ii^j0)]
  {
    dft16<1>(vr, vi);
#pragma unroll
    for (int j0 = 1; j0 < 16; ++j0) twiddle(vr[j0], vi[j0], C2i * (float)(ii * j0));
#pragma unroll
    for (int j0 = 0; j0 < 16; ++j0)
      S[256 * j0 + 16 * rr + (ii ^ j0)] = make_float2(vr[j0], vi[j0]);
  }
  __syncthreads();
  // inv stage B: read S[256*ii+16*rr+(r2^ii)]; DFT16; *W4096^{+rr*(ii+16*j1)}
  {
#pragma unroll
    for (int r2 = 0; r2 < 16; ++r2) {
      const float2 t = S[256 * ii + 16 * rr + (r2 ^ ii)];
      vr[r2] = t.x; vi[r2] = t.y;
    }
    __syncthreads();  // WAR
    dft16<1>(vr, vi);
#pragma unroll
    for (int j1 = 0; j1 < 16; ++j1)
      twiddle(vr[j1], vi[j1], C1i * (float)(rr * (ii + 16 * j1)));
#pragma unroll
    for (int j1 = 0; j1 < 16; ++j1)
      S[256 * rr + ii + 16 * j1] = make_float2(vr[j1], vi[j1]);
  }
  __syncthreads();
  // inv stage C: thread j: u[r]=S[256r+j]; DFT16; z[j+256a] (1/N in T2)
  {
    const int j = tid;
#pragma unroll
    for (int r = 0; r < 16; ++r) {
      const float2 t = S[256 * r + j];
      vr[r] = t.x; vi[r] = t.y;
    }
    dft16<1>(vr, vi);
#pragma unroll
    for (int a = 0; a < 16; ++a) Zrow[j + 256 * a] = make_float2(vr[a], vi[a]);
  }
}

// ---- T2: Z[b,g,t] -> y[b,t,d], * amp/4096 ----
__global__ __launch_bounds__(256, 8) void k_unpack_t(const float2* __restrict__ Z,
                                                     const float2* __restrict__ amp2,
                                                     float2* __restrict__ y2) {
  __shared__ float2 tile[64][33];
  const int tid = threadIdx.x;
  const int g0 = blockIdx.x * 32;
  const int t0 = blockIdx.y * 64;
  const int b = blockIdx.z;
#pragma unroll
  for (int it = 0; it < 8; ++it) {
    const int l = tid + 256 * it;
    const int gg = l >> 6, tt = l & 63;
    tile[tt][gg] = Z[((size_t)b * D2_ + g0 + gg) * T_ + t0 + tt];
  }
  __syncthreads();
#pragma unroll
  for (int it = 0; it < 8; ++it) {
    const int l = tid + 256 * it;
    const int r = l >> 5, c = l & 31;
    const float2 t = tile[r][c];
    const float2 av = amp2[g0 + c];
    constexpr float invN = 1.0f / 4096.0f;
    y2[((size_t)b * T_ + t0 + r) * D2_ + g0 + c] =
        make_float2(t.x * av.x * invN, t.y * av.y * invN);
  }
}

extern "C" void kernel_launch(void* const* d_in, const int* in_sizes, int n_in,
                              void* d_out, int out_size, void* d_ws, size_t ws_size,
                              hipStream_t stream) {
  const float* x = (const float*)d_in[0];
  const float* W1 = (const float*)d_in[1];
  const float* b1 = (const float*)d_in[2];
  const float* W2 = (const float*)d_in[3];
  const float* b2 = (const float*)d_in[4];
  const float* amp = (const float*)d_in[5];
  float* out = (float*)d_out;

  float2* Z = (float2*)d_ws;  // 64 MB
  float2* HTS = (float2*)((char*)d_ws + (size_t)B_ * D2_ * T_ * sizeof(float2));  // 16 MB
  float* h = (float*)((char*)HTS + (size_t)D2_ * 4096 * sizeof(float2));  // 262 KB

  k_filter_h<<<dim3((NBINS + 255) / 256), 256, 0, stream>>>(W1, b1, h);
  k_filter_HTS<<<dim3(16, D2_), 256, 0, stream>>>(h, W2, b2, HTS);
  k_pack_t<<<dim3(D2_ / 32, T_ / 64, B_), 256, 0, stream>>>((const float2*)x, Z);
  k_fft_fused<<<dim3(D2_, B_), 256, 0, stream>>>(Z, HTS);
  k_unpack_t<<<dim3(D2_ / 32, T_ / 64, B_), 256, 0, stream>>>(Z, (const float2*)amp,
                                                              (float2*)out);
}